// Round 4
// baseline (71.131 us; speedup 1.0000x reference)
//
#include <hip/hip_runtime.h>

// Deformable Conv1d via implicit GEMM on MFMA (bf16 in, fp32 acc).
// out[b,o,t] = sum_{ck} w[o][ck] * xs[b][ck][t],  ck = c*3+k,
// xs[ck][t] = mask[b,k,t]*(G0*x[b,c,U] + G1*x[b,c,U+1]) (constrained sampling,
//             U in {t,t+1,t+2} -> 4-tap window -> coef[k][d][t] form).
// R4: (1) 32B-per-thread output stores (float2+float4+float2, phase-8 rows)
//     (2) coef-LDS + aligned float4 x loads (12x fewer gather VMEM instrs)
//     (3) XCD-chunked block swizzle (b-pair per XCD; x slab L2-resident)
#define BB 16
#define CI 128
#define CO 128
#define LL 4096
#define LOUT 4094
#define CK 384           // CI*3 = GEMM K
#define TT 64            // t-tile per block (GEMM N)
#define NTILE 64
#define OPAD 65          // obuf row stride (floats)

typedef short short8 __attribute__((ext_vector_type(8)));
typedef float floatx4 __attribute__((ext_vector_type(4)));

__device__ __forceinline__ ushort f2bf(float f) {   // RNE f32 -> bf16
    union { float f; uint u; } v; v.f = f;
    uint r = v.u + 0x7FFFu + ((v.u >> 16) & 1u);
    return (ushort)(r >> 16);
}

__global__ __launch_bounds__(256, 3)
void dconv1d_mfma_kernel(const float* __restrict__ x,
                         const float* __restrict__ offs,
                         const float* __restrict__ mask,
                         const float* __restrict__ w,
                         const float* __restrict__ bias,
                         float* __restrict__ out) {
    // xs tile: [t][ck] bf16, XOR-swizzled cols: col' = col ^ ((t&15)<<3). 48 KB.
    // Reused as fp32 obuf[128][OPAD] (33.3 KB) in the epilogue.
    __shared__ ushort xs[TT][CK];
    __shared__ float coef[3][4][TT];     // 3 KB: per-(k,t) 4-tap coeffs (mask folded)

    const int tid  = threadIdx.x;
    const int lane = tid & 63;
    const int wv   = tid >> 6;           // wave 0..3 -> o-rows [wv*32, wv*32+32)
    const int bid  = blockIdx.x;
    // XCD-chunked swizzle: XCD k (= bid%8) owns lb in [k*128,(k+1)*128)
    // = b in {2k,2k+1}, all 64 t-tiles. Bijective over 1024.
    const int lb   = (bid & 7) * 128 + (bid >> 3);
    const int b    = lb >> 6;
    const int t0   = (lb & 63) * TT;

    // ---- A fragments: w[o][ck] -> registers, bf16. 16x16x32 layout:
    // lane holds A[row = lane&15][k = (lane>>4)*8 + j], j=0..7.
    short8 afrag[2][12];
    {
        const int arow = wv * 32 + (lane & 15);
        const int ack  = (lane >> 4) * 8;
#pragma unroll 4
        for (int mf = 0; mf < 2; ++mf) {
            const float* wp = w + (size_t)(arow + mf * 16) * CK + ack;
#pragma unroll 4
            for (int ks = 0; ks < 12; ++ks) {
                floatx4 v0 = *(const floatx4*)(wp + ks * 32);
                floatx4 v1 = *(const floatx4*)(wp + ks * 32 + 4);
                union { uint u[4]; short8 s; } r;
                r.u[0] = (uint)f2bf(v0[0]) | ((uint)f2bf(v0[1]) << 16);
                r.u[1] = (uint)f2bf(v0[2]) | ((uint)f2bf(v0[3]) << 16);
                r.u[2] = (uint)f2bf(v1[0]) | ((uint)f2bf(v1[1]) << 16);
                r.u[3] = (uint)f2bf(v1[2]) | ((uint)f2bf(v1[3]) << 16);
                afrag[mf][ks] = r.s;
            }
        }
    }

    // ---- phase 0: coef[k][d][t] (exact reference fp32 op order, mask folded) ----
    if (tid < 3 * TT) {
        const int t  = tid & (TT - 1);
        const int k  = tid >> 6;               // 0..2
        const int gt = t0 + t;
        float c0 = 0.f, c1 = 0.f, c2 = 0.f, c3 = 0.f;
        if (gt < LOUT) {
            const float ofv = offs[((size_t)b * LOUT + gt) * 3 + k];
            const float mv  = mask[((size_t)b * 3 + k) * LOUT + gt];
            const float gtf = (float)gt;
            float T = (gtf + (float)k) + ofv;          // t0s + dil_pos + offsets
            T = fminf(fmaxf(T, gtf), gtf + 2.0f);      // clamp to receptive field
            int U = (int)floorf(T);
            if (U > LL - 2) U = LL - 2;                // clip(., 0, l-2)
            const float Uf = (float)U;
            const float G0 = fmaxf(0.f, 1.f - fabsf(Uf - T)) * mv;
            const float G1 = fmaxf(0.f, 1.f - fabsf(Uf + 1.f - T)) * mv;
            const int d0 = U - gt;                     // 0..2
            c0 = (d0 == 0) ? G0 : 0.f;
            c1 = (d0 == 0) ? G1 : ((d0 == 1) ? G0 : 0.f);
            c2 = (d0 == 1) ? G1 : ((d0 == 2) ? G0 : 0.f);
            c3 = (d0 == 2) ? G1 : 0.f;
        }
        coef[k][0][t] = c0; coef[k][1][t] = c1;
        coef[k][2][t] = c2; coef[k][3][t] = c3;
    }
    __syncthreads();

    // ---- build xs tile: one unit/thread: t-quad t4 = tid&15, c-group cg = tid>>4.
    // Per channel: aligned float4 pair covers x[c][base..base+7] (4-tap windows
    // for t = t4*4..t4*4+3). Tail clamp is safe: clamped lanes only multiply
    // zero coefs (U clip at LL-2 forces d0<3 there).
    {
        const int t4   = tid & 15;
        const int cg   = tid >> 4;
        const int base = t0 + t4 * 4;
        const int base2 = (base + 8 <= LL) ? (base + 4) : (LL - 4);
        const float* px = x + ((size_t)b * CI + cg * 8) * LL;
        uint dwbuf[4][12];                 // [j][contiguous ck-dwords], static idx
#pragma unroll
        for (int cp = 0; cp < 4; ++cp) {   // channel pairs
            const float* p0 = px + (size_t)(cp * 2) * LL;
            const float* p1 = p0 + LL;
            floatx4 a0 = *(const floatx4*)(p0 + base);
            floatx4 b0 = *(const floatx4*)(p0 + base2);
            floatx4 a1 = *(const floatx4*)(p1 + base);
            floatx4 b1 = *(const floatx4*)(p1 + base2);
            float xw0[8] = {a0[0],a0[1],a0[2],a0[3], b0[0],b0[1],b0[2],b0[3]};
            float xw1[8] = {a1[0],a1[1],a1[2],a1[3], b1[0],b1[1],b1[2],b1[3]};
#pragma unroll
            for (int j = 0; j < 4; ++j) {
                const int t = t4 * 4 + j;
                ushort v[6];
#pragma unroll
                for (int k = 0; k < 3; ++k) {
                    const float k0 = coef[k][0][t], k1 = coef[k][1][t];
                    const float k2 = coef[k][2][t], k3 = coef[k][3][t];
                    float s0 = k0*xw0[j] + k1*xw0[j+1] + k2*xw0[j+2] + k3*xw0[j+3];
                    float s1 = k0*xw1[j] + k1*xw1[j+1] + k2*xw1[j+2] + k3*xw1[j+3];
                    v[k]     = f2bf(s0);   // ck = (2cp)*3 + k
                    v[3 + k] = f2bf(s1);   // ck = (2cp+1)*3 + k
                }
                dwbuf[j][cp*3 + 0] = (uint)v[0] | ((uint)v[1] << 16);
                dwbuf[j][cp*3 + 1] = (uint)v[2] | ((uint)v[3] << 16);
                dwbuf[j][cp*3 + 2] = (uint)v[4] | ((uint)v[5] << 16);
            }
        }
#pragma unroll
        for (int j = 0; j < 4; ++j) {
            const int t   = t4 * 4 + j;
            const int swz = (t & 15) << 3;
#pragma unroll
            for (int s = 0; s < 3; ++s) {
                const int col = (cg * 24 + s * 8) ^ swz;   // 8-aligned, bijective
                uint4 q; q.x = dwbuf[j][s*4]; q.y = dwbuf[j][s*4+1];
                q.z = dwbuf[j][s*4+2]; q.w = dwbuf[j][s*4+3];
                *(uint4*)(&xs[t][col]) = q;
            }
        }
    }
    __syncthreads();

    // ---- GEMM: acc[mf][nf] over 12 k-steps of 32 ----
    floatx4 zero4 = {0.f, 0.f, 0.f, 0.f};
    floatx4 acc[2][4];
#pragma unroll
    for (int mf = 0; mf < 2; ++mf)
#pragma unroll
        for (int nf = 0; nf < 4; ++nf) acc[mf][nf] = zero4;

    const int bswz = (lane & 15) << 3;
#pragma unroll
    for (int ks = 0; ks < 12; ++ks) {
        short8 bfr[4];
#pragma unroll
        for (int nf = 0; nf < 4; ++nf) {
            const int tb  = nf * 16 + (lane & 15);     // B col = lane&15
            const int col = (ks * 32 + (lane >> 4) * 8) ^ bswz;
            bfr[nf] = *(const short8*)(&xs[tb][col]);
        }
#pragma unroll
        for (int mf = 0; mf < 2; ++mf)
#pragma unroll
            for (int nf = 0; nf < 4; ++nf)
                acc[mf][nf] = __builtin_amdgcn_mfma_f32_16x16x32_bf16(
                    afrag[mf][ks], bfr[nf], acc[mf][nf], 0, 0, 0);
    }

    // ---- epilogue: stage D tile in LDS (D: col=lane&15 -> t, row=(lane>>4)*4+r -> o) ----
    __syncthreads();                         // all xs reads done before reuse
    float* obuf = (float*)&xs[0][0];         // [CO][OPAD]
#pragma unroll
    for (int mf = 0; mf < 2; ++mf)
#pragma unroll
        for (int nf = 0; nf < 4; ++nf) {
            const int t = nf * 16 + (lane & 15);
#pragma unroll
            for (int r = 0; r < 4; ++r) {
                const int o = wv * 32 + mf * 16 + (lane >> 4) * 4 + r;
                obuf[o * OPAD + t] = acc[mf][nf][r];
            }
        }
    __syncthreads();

    // ---- 32B-contiguous per-thread stores. Row byte phase is 8 (mod 16):
    // emit float2 | float4(16B-aligned) | float2. Only the very last pair of
    // the last tile (gt=4094,4095) is masked.
#pragma unroll
    for (int it = 0; it < 4; ++it) {
        const int f   = it * 256 + tid;
        const int o   = f >> 3;
        const int seg = f & 7;
        const int tb  = t0 + seg * 8;
        const float bv = bias[o];
        const float* src = obuf + o * OPAD + seg * 8;
        float* dst = out + ((size_t)b * CO + o) * LOUT + tb;
        float2 h; h.x = src[0] + bv; h.y = src[1] + bv;
        *(float2*)dst = h;                               // phase 8
        float4 m4; m4.x = src[2] + bv; m4.y = src[3] + bv;
        m4.z = src[4] + bv; m4.w = src[5] + bv;
        *(float4*)(dst + 2) = m4;                        // phase 0: aligned 16B
        if (tb + 6 < LOUT) {
            float2 tl; tl.x = src[6] + bv; tl.y = src[7] + bv;
            *(float2*)(dst + 6) = tl;
        }
    }
}

extern "C" void kernel_launch(void* const* d_in, const int* in_sizes, int n_in,
                              void* d_out, int out_size, void* d_ws, size_t ws_size,
                              hipStream_t stream) {
    const float* x    = (const float*)d_in[0];
    const float* offs = (const float*)d_in[1];
    const float* mask = (const float*)d_in[2];
    const float* w    = (const float*)d_in[3];
    const float* bias = (const float*)d_in[4];
    float* out = (float*)d_out;

    dim3 grid(BB * NTILE);   // 1024 blocks
    dim3 block(256);
    dconv1d_mfma_kernel<<<grid, block, 0, stream>>>(x, offs, mask, w, bias, out);
}

// Round 5
// 46.454 us; speedup vs baseline: 1.5312x; 1.5312x over previous
//
#include <hip/hip_runtime.h>

// Deformable Conv1d via implicit GEMM on MFMA (bf16 in, fp32 acc).
// out[b,o,t] = sum_{ck} w[o][ck] * xs[b][ck][t],  ck = c*3+k,
// xs[ck][t] = mask[b,k,t] * (G0*x[b,c,U] + G1*x[b,c,U+1])  (constrained sampling)
// R5: NO persistent afrag (R2-R4 spilled 96 VGPRs of A-frags to scratch ->
//     ~100 MB/launch of scratch HBM write+reload traffic, the real 4x "write
//     amp"). A-slices are reloaded from L2-hot w inside the k-loop instead.
#define BB 16
#define CI 128
#define CO 128
#define LL 4096
#define LOUT 4094
#define CK 384           // CI*3 = GEMM K
#define TT 64            // t-tile per block (GEMM N)
#define NTILE 64
#define OPAD 65          // obuf row stride (floats)

typedef short short8 __attribute__((ext_vector_type(8)));
typedef float floatx4 __attribute__((ext_vector_type(4)));

__device__ __forceinline__ ushort f2bf(float f) {   // RNE f32 -> bf16
    union { float f; uint u; } v; v.f = f;
    uint r = v.u + 0x7FFFu + ((v.u >> 16) & 1u);
    return (ushort)(r >> 16);
}

__global__ __launch_bounds__(256, 3)
void dconv1d_mfma_kernel(const float* __restrict__ x,
                         const float* __restrict__ offs,
                         const float* __restrict__ mask,
                         const float* __restrict__ w,
                         const float* __restrict__ bias,
                         float* __restrict__ out) {
    // xs tile: [t][ck] bf16, XOR-swizzled cols: col' = col ^ ((t&15)<<3). 48 KB.
    // Reused as fp32 obuf[128][OPAD] (33.3 KB) in the epilogue.
    __shared__ ushort xs[TT][CK];

    const int tid  = threadIdx.x;
    const int lane = tid & 63;
    const int wv   = tid >> 6;          // wave 0..3 -> o-rows [wv*32, wv*32+32)
    const int bid  = blockIdx.x;
    // XCD-chunked swizzle: XCD k (= bid%8) owns lb in [k*128,(k+1)*128)
    // = b in {2k,2k+1}, all 64 t-tiles. Bijective over 1024.
    const int lb   = (bid & 7) * 128 + (bid >> 3);
    const int b    = lb >> 6;
    const int t0   = (lb & 63) * TT;

    // ---- build xs tile: unit = (t, c-group of 8). 1024 units / 256 threads. ----
    for (int it = 0; it < 4; ++it) {
        const int u  = tid + it * 256;
        const int t  = u & (TT - 1);
        const int cg = u >> 6;                 // 0..15
        const int gt = t0 + t;

        float g0[3], g1[3];
        int   U[3];
#pragma unroll
        for (int k = 0; k < 3; ++k) {
            float ofv = 0.f, mv = 0.f;
            if (gt < LOUT) {
                ofv = offs[((size_t)b * LOUT + gt) * 3 + k];
                mv  = mask[((size_t)b * 3 + k) * LOUT + gt];
            }
            const float gtf = (float)gt;
            float T = (gtf + (float)k) + ofv;          // exact ref op order
            T = fminf(fmaxf(T, gtf), gtf + 2.0f);      // clamp to receptive field
            int Ui = (int)floorf(T);
            if (Ui > LL - 2) Ui = LL - 2;
            const float Uf = (float)Ui;
            g0[k] = fmaxf(0.f, 1.f - fabsf(Uf - T)) * mv;
            g1[k] = fmaxf(0.f, 1.f - fabsf(Uf + 1.f - T)) * mv;
            U[k] = Ui;
        }

        ushort vals[24];
#pragma unroll
        for (int ci = 0; ci < 8; ++ci) {
            const float* xr = x + ((size_t)b * CI + cg * 8 + ci) * LL;
#pragma unroll
            for (int k = 0; k < 3; ++k) {
                const float x0 = xr[U[k]];
                const float x1 = xr[U[k] + 1];         // U <= LL-2 -> in bounds
                vals[ci * 3 + k] = f2bf(g0[k] * x0 + g1[k] * x1);
            }
        }
        uint dw[12];
#pragma unroll
        for (int j = 0; j < 12; ++j)
            dw[j] = (uint)vals[2 * j] | ((uint)vals[2 * j + 1] << 16);
        const int swz = (t & 15) << 3;
#pragma unroll
        for (int j = 0; j < 3; ++j) {
            const int col = (cg * 24 + j * 8) ^ swz;   // 8-aligned, bijective
            uint4 q; q.x = dw[4*j]; q.y = dw[4*j+1]; q.z = dw[4*j+2]; q.w = dw[4*j+3];
            *(uint4*)(&xs[t][col]) = q;
        }
    }
    __syncthreads();

    // ---- GEMM: 12 k-steps of 32; A-slice reloaded from L2-hot w each step ----
    floatx4 zero4 = {0.f, 0.f, 0.f, 0.f};
    floatx4 acc[2][4];
#pragma unroll
    for (int mf = 0; mf < 2; ++mf)
#pragma unroll
        for (int nf = 0; nf < 4; ++nf) acc[mf][nf] = zero4;

    const int arow = wv * 32 + (lane & 15);    // A row = lane&15
    const int ack  = (lane >> 4) * 8;          // A k  = (lane>>4)*8 + j
    const int bswz = (lane & 15) << 3;

#pragma unroll 2
    for (int ks = 0; ks < 12; ++ks) {
        short8 afr[2];
#pragma unroll
        for (int mf = 0; mf < 2; ++mf) {
            const float* wp = w + (size_t)(arow + mf * 16) * CK + ks * 32 + ack;
            floatx4 v0 = *(const floatx4*)(wp);
            floatx4 v1 = *(const floatx4*)(wp + 4);
            union { uint u[4]; short8 s; } r;
            r.u[0] = (uint)f2bf(v0[0]) | ((uint)f2bf(v0[1]) << 16);
            r.u[1] = (uint)f2bf(v0[2]) | ((uint)f2bf(v0[3]) << 16);
            r.u[2] = (uint)f2bf(v1[0]) | ((uint)f2bf(v1[1]) << 16);
            r.u[3] = (uint)f2bf(v1[2]) | ((uint)f2bf(v1[3]) << 16);
            afr[mf] = r.s;
        }
        short8 bfr[4];
#pragma unroll
        for (int nf = 0; nf < 4; ++nf) {
            const int tb  = nf * 16 + (lane & 15);     // B col = lane&15
            const int col = (ks * 32 + (lane >> 4) * 8) ^ bswz;
            bfr[nf] = *(const short8*)(&xs[tb][col]);
        }
#pragma unroll
        for (int mf = 0; mf < 2; ++mf)
#pragma unroll
            for (int nf = 0; nf < 4; ++nf)
                acc[mf][nf] = __builtin_amdgcn_mfma_f32_16x16x32_bf16(
                    afr[mf], bfr[nf], acc[mf][nf], 0, 0, 0);
    }

    // ---- epilogue: stage D tile in LDS (D: col=lane&15 -> t, row=(lane>>4)*4+r -> o) ----
    __syncthreads();                         // all xs reads done before reuse
    float* obuf = (float*)&xs[0][0];         // [CO][OPAD]
#pragma unroll
    for (int mf = 0; mf < 2; ++mf)
#pragma unroll
        for (int nf = 0; nf < 4; ++nf) {
            const int t = nf * 16 + (lane & 15);
#pragma unroll
            for (int r = 0; r < 4; ++r) {
                const int o = wv * 32 + mf * 16 + (lane >> 4) * 4 + r;
                obuf[o * OPAD + t] = acc[mf][nf][r];
            }
        }
    __syncthreads();

    // 4096 float2 = 128 rows x 32; 32 consecutive threads stream one row (256 B).
#pragma unroll 4
    for (int it = 0; it < 16; ++it) {
        const int f  = it * 256 + tid;
        const int o  = f >> 5;
        const int j  = f & 31;
        const int gt = t0 + 2 * j;
        if (gt < LOUT) {                     // LOUT even -> pair fully in-bounds
            const float bv = bias[o];
            float2 v;
            v.x = obuf[o * OPAD + 2 * j]     + bv;
            v.y = obuf[o * OPAD + 2 * j + 1] + bv;
            *(float2*)(out + ((size_t)b * CO + o) * LOUT + gt) = v;   // 8B-aligned
        }
    }
}

extern "C" void kernel_launch(void* const* d_in, const int* in_sizes, int n_in,
                              void* d_out, int out_size, void* d_ws, size_t ws_size,
                              hipStream_t stream) {
    const float* x    = (const float*)d_in[0];
    const float* offs = (const float*)d_in[1];
    const float* mask = (const float*)d_in[2];
    const float* w    = (const float*)d_in[3];
    const float* bias = (const float*)d_in[4];
    float* out = (float*)d_out;

    dim3 grid(BB * NTILE);   // 1024 blocks
    dim3 block(256);
    dconv1d_mfma_kernel<<<grid, block, 0, stream>>>(x, offs, mask, w, bias, out);
}

// Round 6
// 44.272 us; speedup vs baseline: 1.6067x; 1.0493x over previous
//
#include <hip/hip_runtime.h>

// Deformable Conv1d via implicit GEMM on MFMA (bf16 in, fp32 acc).
// out[b,o,t] = sum_{ck} w[o][ck] * xs[b][ck][t],  ck = c*3+k,
// xs[ck][t] = mask[b,k,t]*(G0*x[b,c,U] + G1*x[b,c,U+1]) (constrained sampling,
//             U in {t,t+1,t+2} -> 4-tap window -> coef[k][d][t] form).
// R6: (1) w pre-converted to bf16 once into d_ws (no per-block f2bf VALU)
//     (2) coef-LDS xs-build: sampling math deduped 16x, gathers = 16 aligned
//         dwordx4/thread instead of 192 scalar loads (kills the latency chain)
//     Scratch-spill lesson (R2-R5): no big persistent per-thread arrays.
#define BB 16
#define CI 128
#define CO 128
#define LL 4096
#define LOUT 4094
#define CK 384           // CI*3 = GEMM K
#define TT 64            // t-tile per block (GEMM N)
#define NTILE 64
#define OPAD 65          // obuf row stride (floats)

typedef short short8 __attribute__((ext_vector_type(8)));
typedef float floatx4 __attribute__((ext_vector_type(4)));

__device__ __forceinline__ ushort f2bf(float f) {   // RNE f32 -> bf16
    union { float f; uint u; } v; v.f = f;
    uint r = v.u + 0x7FFFu + ((v.u >> 16) & 1u);
    return (ushort)(r >> 16);
}

// ---- kernel A: w f32 -> bf16 into d_ws (49152 elems, 8/thread) ----
__global__ __launch_bounds__(256)
void wcvt_kernel(const float* __restrict__ w, ushort* __restrict__ wbf) {
    const int i = (blockIdx.x * 256 + threadIdx.x) * 8;
    floatx4 a = *(const floatx4*)(w + i);
    floatx4 b = *(const floatx4*)(w + i + 4);
    uint4 q;
    q.x = (uint)f2bf(a[0]) | ((uint)f2bf(a[1]) << 16);
    q.y = (uint)f2bf(a[2]) | ((uint)f2bf(a[3]) << 16);
    q.z = (uint)f2bf(b[0]) | ((uint)f2bf(b[1]) << 16);
    q.w = (uint)f2bf(b[2]) | ((uint)f2bf(b[3]) << 16);
    *(uint4*)(wbf + i) = q;
}

__global__ __launch_bounds__(256, 3)
void dconv1d_mfma_kernel(const float* __restrict__ x,
                         const float* __restrict__ offs,
                         const float* __restrict__ mask,
                         const ushort* __restrict__ wbf,
                         const float* __restrict__ bias,
                         float* __restrict__ out) {
    // xs tile: [t][ck] bf16, XOR-swizzled cols: col' = col ^ ((t&15)<<3). 48 KB.
    // Reused as fp32 obuf[128][OPAD] (33.3 KB) in the epilogue.
    __shared__ ushort xs[TT][CK];
    __shared__ float coef[3][4][TT];     // 3 KB: per-(k,t) 4-tap coeffs (mask folded)

    const int tid  = threadIdx.x;
    const int lane = tid & 63;
    const int wv   = tid >> 6;          // wave 0..3 -> o-rows [wv*32, wv*32+32)
    const int bid  = blockIdx.x;
    // XCD-chunked swizzle: XCD k (= bid%8) owns lb in [k*128,(k+1)*128)
    // = b in {2k,2k+1}, all 64 t-tiles. Bijective over 1024.
    const int lb   = (bid & 7) * 128 + (bid >> 3);
    const int b    = lb >> 6;
    const int t0   = (lb & 63) * TT;

    // ---- phase 0: coef[k][d][t] (exact reference fp32 op order, mask folded) ----
    if (tid < 3 * TT) {
        const int t  = tid & (TT - 1);
        const int k  = tid >> 6;               // 0..2
        const int gt = t0 + t;
        float c0 = 0.f, c1 = 0.f, c2 = 0.f, c3 = 0.f;
        if (gt < LOUT) {
            const float ofv = offs[((size_t)b * LOUT + gt) * 3 + k];
            const float mv  = mask[((size_t)b * 3 + k) * LOUT + gt];
            const float gtf = (float)gt;
            float T = (gtf + (float)k) + ofv;          // t0s + dil_pos + offsets
            T = fminf(fmaxf(T, gtf), gtf + 2.0f);      // clamp to receptive field
            int U = (int)floorf(T);
            if (U > LL - 2) U = LL - 2;                // clip(., 0, l-2)
            const float Uf = (float)U;
            const float G0 = fmaxf(0.f, 1.f - fabsf(Uf - T)) * mv;
            const float G1 = fmaxf(0.f, 1.f - fabsf(Uf + 1.f - T)) * mv;
            const int d0 = U - gt;                     // 0..2
            c0 = (d0 == 0) ? G0 : 0.f;
            c1 = (d0 == 0) ? G1 : ((d0 == 1) ? G0 : 0.f);
            c2 = (d0 == 1) ? G1 : ((d0 == 2) ? G0 : 0.f);
            c3 = (d0 == 2) ? G1 : 0.f;
        }
        coef[k][0][t] = c0; coef[k][1][t] = c1;
        coef[k][2][t] = c2; coef[k][3][t] = c3;
    }
    __syncthreads();

    // ---- build xs tile: one unit/thread: t-quad t4 = tid&15, c-group cg = tid>>4.
    // Aligned float4 pair covers x[c][base..base+7] (4-tap windows for
    // t = t4*4..t4*4+3). Tail clamp safe: clamped lanes multiply zero coefs.
    {
        const int t4   = tid & 15;
        const int cg   = tid >> 4;
        const int base = t0 + t4 * 4;
        const int base2 = (base + 8 <= LL) ? (base + 4) : (LL - 4);
        const float* px = x + ((size_t)b * CI + cg * 8) * LL;
        uint dwbuf[4][12];                 // [j][contiguous ck-dwords], static idx
#pragma unroll
        for (int cp = 0; cp < 4; ++cp) {   // channel pairs
            const float* p0 = px + (size_t)(cp * 2) * LL;
            const float* p1 = p0 + LL;
            floatx4 a0 = *(const floatx4*)(p0 + base);
            floatx4 b0 = *(const floatx4*)(p0 + base2);
            floatx4 a1 = *(const floatx4*)(p1 + base);
            floatx4 b1 = *(const floatx4*)(p1 + base2);
            float xw0[8] = {a0[0],a0[1],a0[2],a0[3], b0[0],b0[1],b0[2],b0[3]};
            float xw1[8] = {a1[0],a1[1],a1[2],a1[3], b1[0],b1[1],b1[2],b1[3]};
#pragma unroll
            for (int j = 0; j < 4; ++j) {
                const int t = t4 * 4 + j;
                ushort v[6];
#pragma unroll
                for (int k = 0; k < 3; ++k) {
                    const float k0 = coef[k][0][t], k1 = coef[k][1][t];
                    const float k2 = coef[k][2][t], k3 = coef[k][3][t];
                    float s0 = k0*xw0[j] + k1*xw0[j+1] + k2*xw0[j+2] + k3*xw0[j+3];
                    float s1 = k0*xw1[j] + k1*xw1[j+1] + k2*xw1[j+2] + k3*xw1[j+3];
                    v[k]     = f2bf(s0);   // ck = (2cp)*3 + k
                    v[3 + k] = f2bf(s1);   // ck = (2cp+1)*3 + k
                }
                dwbuf[j][cp*3 + 0] = (uint)v[0] | ((uint)v[1] << 16);
                dwbuf[j][cp*3 + 1] = (uint)v[2] | ((uint)v[3] << 16);
                dwbuf[j][cp*3 + 2] = (uint)v[4] | ((uint)v[5] << 16);
            }
        }
#pragma unroll
        for (int j = 0; j < 4; ++j) {
            const int t   = t4 * 4 + j;
            const int swz = (t & 15) << 3;
#pragma unroll
            for (int s = 0; s < 3; ++s) {
                const int col = (cg * 24 + s * 8) ^ swz;   // 8-aligned, bijective
                uint4 q; q.x = dwbuf[j][s*4]; q.y = dwbuf[j][s*4+1];
                q.z = dwbuf[j][s*4+2]; q.w = dwbuf[j][s*4+3];
                *(uint4*)(&xs[t][col]) = q;
            }
        }
    }
    __syncthreads();

    // ---- GEMM: 12 k-steps of 32; A-slice = bare 16B load from L2-hot wbf ----
    floatx4 zero4 = {0.f, 0.f, 0.f, 0.f};
    floatx4 acc[2][4];
#pragma unroll
    for (int mf = 0; mf < 2; ++mf)
#pragma unroll
        for (int nf = 0; nf < 4; ++nf) acc[mf][nf] = zero4;

    const int arow = wv * 32 + (lane & 15);    // A row = lane&15
    const int ack  = (lane >> 4) * 8;          // A k  = (lane>>4)*8 + j
    const int bswz = (lane & 15) << 3;

#pragma unroll 2
    for (int ks = 0; ks < 12; ++ks) {
        short8 afr[2];
#pragma unroll
        for (int mf = 0; mf < 2; ++mf)
            afr[mf] = *(const short8*)(wbf + (size_t)(arow + mf * 16) * CK + ks * 32 + ack);
        short8 bfr[4];
#pragma unroll
        for (int nf = 0; nf < 4; ++nf) {
            const int tb  = nf * 16 + (lane & 15);     // B col = lane&15
            const int col = (ks * 32 + (lane >> 4) * 8) ^ bswz;
            bfr[nf] = *(const short8*)(&xs[tb][col]);
        }
#pragma unroll
        for (int mf = 0; mf < 2; ++mf)
#pragma unroll
            for (int nf = 0; nf < 4; ++nf)
                acc[mf][nf] = __builtin_amdgcn_mfma_f32_16x16x32_bf16(
                    afr[mf], bfr[nf], acc[mf][nf], 0, 0, 0);
    }

    // ---- epilogue: stage D tile in LDS (D: col=lane&15 -> t, row=(lane>>4)*4+r -> o) ----
    __syncthreads();                         // all xs reads done before reuse
    float* obuf = (float*)&xs[0][0];         // [CO][OPAD]
#pragma unroll
    for (int mf = 0; mf < 2; ++mf)
#pragma unroll
        for (int nf = 0; nf < 4; ++nf) {
            const int t = nf * 16 + (lane & 15);
#pragma unroll
            for (int r = 0; r < 4; ++r) {
                const int o = wv * 32 + mf * 16 + (lane >> 4) * 4 + r;
                obuf[o * OPAD + t] = acc[mf][nf][r];
            }
        }
    __syncthreads();

    // 4096 float2 = 128 rows x 32; 32 consecutive threads stream one row (256 B).
#pragma unroll 4
    for (int it = 0; it < 16; ++it) {
        const int f  = it * 256 + tid;
        const int o  = f >> 5;
        const int j  = f & 31;
        const int gt = t0 + 2 * j;
        if (gt < LOUT) {                     // LOUT even -> pair fully in-bounds
            const float bv = bias[o];
            float2 v;
            v.x = obuf[o * OPAD + 2 * j]     + bv;
            v.y = obuf[o * OPAD + 2 * j + 1] + bv;
            *(float2*)(out + ((size_t)b * CO + o) * LOUT + gt) = v;   // 8B-aligned
        }
    }
}

extern "C" void kernel_launch(void* const* d_in, const int* in_sizes, int n_in,
                              void* d_out, int out_size, void* d_ws, size_t ws_size,
                              hipStream_t stream) {
    const float* x    = (const float*)d_in[0];
    const float* offs = (const float*)d_in[1];
    const float* mask = (const float*)d_in[2];
    const float* w    = (const float*)d_in[3];
    const float* bias = (const float*)d_in[4];
    float* out = (float*)d_out;
    ushort* wbf = (ushort*)d_ws;             // 98.3 KB of scratch

    wcvt_kernel<<<dim3(CO * CI * 3 / (256 * 8)), dim3(256), 0, stream>>>(w, wbf);
    dim3 grid(BB * NTILE);   // 1024 blocks
    dim3 block(256);
    dconv1d_mfma_kernel<<<grid, block, 0, stream>>>(x, offs, mask, wbf, bias, out);
}